// Round 16
// baseline (1481.589 us; speedup 1.0000x reference)
//
#include <hip/hip_runtime.h>
#include <math.h>

namespace {

constexpr int kB   = 8;
constexpr int kL   = 256;
constexpr int kTok = 2048;   // B*L
constexpr int kDM  = 384;
constexpr int kDI  = 768;
constexpr int kDS  = 16;
constexpr int kDTR = 24;
constexpr int kPROJ = 56;    // DTR + 2*DS
constexpr int kNL  = 12;

constexpr int kWIN  = 2 * kDI * kDM;   // 589824 in_proj weights/layer
constexpr int kWOUT = kDM * kDI;       // 294912
constexpr int kWX   = kPROJ * kDI;     // 43008
constexpr int kWTOT = kWIN + kWOUT + kWX;  // 927744

typedef float f32x4 __attribute__((ext_vector_type(4)));
typedef short short8 __attribute__((ext_vector_type(8)));

__device__ __forceinline__ float softplus_f(float x) {
  return (x > 20.f) ? x : log1pf(__expf(x));
}
__device__ __forceinline__ float silu_f(float x) {
  return x / (1.f + __expf(-x));
}
__device__ __forceinline__ unsigned short f2bf(float f) {
  union { float f; unsigned u; } v; v.f = f;
  unsigned r = v.u + 0x7FFFu + ((v.u >> 16) & 1u);
  return (unsigned short)(r >> 16);
}
__device__ __forceinline__ float bf2f(unsigned short u) {
  return __uint_as_float((unsigned)u << 16);
}

// ------------- patch embed GEMM (+ proj zeroing for layer 0) ---------------
__global__ __launch_bounds__(256) void patch_gemm_k(
    const float* __restrict__ x, const float* __restrict__ Bw,
    const float* __restrict__ bias, const float* __restrict__ pos,
    float* __restrict__ C, float* __restrict__ proj_zero) {
  __shared__ float As[16][68];
  __shared__ float Bs[16][68];
  int tid = threadIdx.x;
  int bm = blockIdx.y * 64;
  int bn = blockIdx.x * 64;
  {
    int bid = blockIdx.y * 6 + blockIdx.x;  // 192 blocks
    for (int i = bid * 256 + tid; i < kTok * kPROJ; i += 192 * 256)
      proj_zero[i] = 0.f;
  }
  int lr = tid >> 2;
  int lk = (tid & 3) << 2;
  int tm = (tid >> 4) << 2;
  int tn = (tid & 15) << 2;
  float acc[4][4] = {};
  for (int k0 = 0; k0 < 256; k0 += 16) {
    {
      int token = bm + lr;
      int b = token >> 8, l = token & 255;
      int h = l >> 3, w = l & 7;
      int p = k0 >> 4;
      const float* ap = x + ((size_t)(b * 512) + h * 16 + p) * 128 + w * 16 + lk;
      float4 av = *(const float4*)ap;
      As[lk + 0][lr] = av.x; As[lk + 1][lr] = av.y;
      As[lk + 2][lr] = av.z; As[lk + 3][lr] = av.w;
    }
    {
      const float* bp = Bw + (size_t)(bn + lr) * 256 + k0 + lk;
      float4 bv = *(const float4*)bp;
      Bs[lk + 0][lr] = bv.x; Bs[lk + 1][lr] = bv.y;
      Bs[lk + 2][lr] = bv.z; Bs[lk + 3][lr] = bv.w;
    }
    __syncthreads();
    #pragma unroll
    for (int k = 0; k < 16; ++k) {
      float4 a = *(const float4*)&As[k][tm];
      float4 b = *(const float4*)&Bs[k][tn];
      float av[4] = {a.x, a.y, a.z, a.w};
      float bv[4] = {b.x, b.y, b.z, b.w};
      #pragma unroll
      for (int i = 0; i < 4; ++i)
        #pragma unroll
        for (int j = 0; j < 4; ++j)
          acc[i][j] = fmaf(av[i], bv[j], acc[i][j]);
    }
    __syncthreads();
  }
  #pragma unroll
  for (int i = 0; i < 4; ++i) {
    int row = bm + tm + i;
    #pragma unroll
    for (int j = 0; j < 4; ++j) {
      int col = bn + tn + j;
      C[(size_t)row * kDM + col] =
          acc[i][j] + bias[col] + pos[(size_t)(row & 255) * kDM + col];
    }
  }
}

// ------------- final layernorm + fused mean-pool (atomicAdd) ---------------
__global__ __launch_bounds__(384) void lnpool_k(
    const float* __restrict__ in, float* __restrict__ pooled,
    const float* __restrict__ g, const float* __restrict__ bb) {
  int t = blockIdx.x, d = threadIdx.x;
  float v = in[(size_t)t * kDM + d];
  float s = v, s2 = v * v;
  #pragma unroll
  for (int m = 32; m >= 1; m >>= 1) {
    s  += __shfl_xor(s, m);
    s2 += __shfl_xor(s2, m);
  }
  __shared__ float ps[6], ps2[6];
  if ((d & 63) == 0) { ps[d >> 6] = s; ps2[d >> 6] = s2; }
  __syncthreads();
  float S = 0.f, S2 = 0.f;
  #pragma unroll
  for (int i = 0; i < 6; ++i) { S += ps[i]; S2 += ps2[i]; }
  float mean = S * (1.f / 384.f);
  float var  = S2 * (1.f / 384.f) - mean * mean;
  float r = rsqrtf(var + 1e-5f);
  float o = (v - mean) * r * g[d] + bb[d];
  atomicAdd(&pooled[(size_t)(t >> 8) * kDM + d], o * (1.f / 256.f));
}

// ------------- convert ALL layers' GEMM weights fp32 -> bf16 (+pool zero) --
__global__ __launch_bounds__(256) void convert_all_k(
    const float* __restrict__ w_in, const float* __restrict__ w_out,
    const float* __restrict__ w_x, unsigned short* __restrict__ dst,
    float* __restrict__ pooled_zero) {
  int layer = blockIdx.y;
  int tid = threadIdx.x;
  if (layer == 0 && blockIdx.x == 0) {
    for (int i = tid; i < kB * kDM; i += 256) pooled_zero[i] = 0.f;
  }
  int i4 = (blockIdx.x * 256 + tid) * 4;
  if (i4 >= kWTOT) return;
  const float* src;
  int off;
  if (i4 < kWIN) { src = w_in + (size_t)layer * kWIN; off = i4; }
  else if (i4 < kWIN + kWOUT) { src = w_out + (size_t)layer * kWOUT; off = i4 - kWIN; }
  else { src = w_x + (size_t)layer * kWX; off = i4 - kWIN - kWOUT; }
  float4 v = *(const float4*)(src + off);
  unsigned short o[4] = {f2bf(v.x), f2bf(v.y), f2bf(v.z), f2bf(v.w)};
  *(uint2*)(dst + (size_t)layer * kWTOT + i4) = *(const uint2*)o;
}

// ------------- FUSED: LN + in_proj + causal conv + SiLU + z-gate + x_proj --
// One block = 32 tokens (+3 halo) x 128 u-channels (d-chunk kb).
// Stage A: LN(tok) MFMA vs [u-chunk | z-chunk] of W_in (N=256, K=384).
//   u_pre -> LDS; z -> silu -> sgT_bf.
// Stage B: causal conv4 + SiLU in LDS -> uT_bf + x_proj A-tile.
// Stage C: MFMA vs Wx chunk (K=128), split-K atomics into proj (pre-zeroed).
// grid (64, 6) = 384 blocks.
__global__ __launch_bounds__(256) void fused1_k(
    const float* __restrict__ tok, const unsigned short* __restrict__ Win,
    const unsigned short* __restrict__ Wx, const float* __restrict__ g,
    const float* __restrict__ bb, const float* __restrict__ cw,
    const float* __restrict__ cb, float* __restrict__ proj,
    unsigned short* __restrict__ uT_bf, unsigned short* __restrict__ sgT_bf) {
  __shared__ float smean[35], srstd[35];
  __shared__ float sg_[kDM], sb_[kDM];
  __shared__ __align__(16) unsigned short As[4][48][8];
  __shared__ __align__(16) unsigned short Bs[4][256][8];
  __shared__ float scw[128][4];
  __shared__ float scb[128];
  __shared__ __align__(16) unsigned short upre[35][128];
  __shared__ __align__(16) unsigned short xa[32][128];
  __shared__ __align__(16) unsigned short Bs2[64][128];

  int tid = threadIdx.x;
  int bm = blockIdx.x * 32;       // token tile base
  int kb = blockIdx.y * 128;      // u-channel chunk
  int wave = tid >> 6, lane = tid & 63;
  int lm = lane & 15, lq = lane >> 4;
  int l0 = bm & 255;              // l of first token in tile

  // LN gamma/beta + conv weights
  for (int i = tid; i < kDM; i += 256) { sg_[i] = g[i]; sb_[i] = bb[i]; }
  if (tid < 128) {
    *(float4*)&scw[tid][0] = *(const float4*)(cw + (size_t)(kb + tid) * 4);
    scb[tid] = cb[kb + tid];
  }
  // LN stats for rows 0..34 (token = bm + r - 3), 4 threads/row
  if (tid < 140) {
    int r = tid >> 2, quarter = tid & 3;
    int t = bm + r - 3;
    int tc = t < 0 ? 0 : t;
    const float* rp = tok + (size_t)tc * kDM + quarter * 96;
    float s = 0.f, s2 = 0.f;
    #pragma unroll
    for (int q = 0; q < 24; ++q) {
      float4 v = ((const float4*)rp)[q];
      s  += v.x + v.y + v.z + v.w;
      s2 += v.x * v.x + v.y * v.y + v.z * v.z + v.w * v.w;
    }
    s  += __shfl_xor(s, 1);  s2 += __shfl_xor(s2, 1);
    s  += __shfl_xor(s, 2);  s2 += __shfl_xor(s2, 2);
    if (quarter == 0) {
      float mean = s * (1.f / 384.f);
      float var  = s2 * (1.f / 384.f) - mean * mean;
      smean[r] = mean;
      srstd[r] = rsqrtf(var + 1e-5f);
    }
  }
  __syncthreads();

  // ---- Stage A: GEMM M=48(35 used) x N=256 x K=384 ----
  int ar = tid >> 2, aq = tid & 3;   // A-stage coords (ar<48 active)
  int wn = wave * 64;
  f32x4 acc[3][4] = {};
  for (int k0 = 0; k0 < kDM; k0 += 32) {
    unsigned short av[8];
    if (ar < 48) {
      int t = bm + ar - 3;
      bool zr = (ar < 3) && (l0 == 0);        // cross-batch / t<0 halo -> 0
      int tc = t < 0 ? 0 : (t > kTok - 1 ? kTok - 1 : t);
      int sidx = ar < 35 ? ar : 34;
      float mean = smean[sidx], rstd = srstd[sidx];
      const float* ap = tok + (size_t)tc * kDM + k0 + aq * 8;
      float4 v0 = ((const float4*)ap)[0];
      float4 v1 = ((const float4*)ap)[1];
      float vv[8] = {v0.x, v0.y, v0.z, v0.w, v1.x, v1.y, v1.z, v1.w};
      #pragma unroll
      for (int j = 0; j < 8; ++j) {
        int k = k0 + aq * 8 + j;
        float val = zr ? 0.f : (vv[j] - mean) * rstd * sg_[k] + sb_[k];
        av[j] = f2bf(val);
      }
    }
    // B: 256 rows (128 u | 128 z), 4 uint4 per thread
    uint4 bv[4];
    {
      int br = tid;
      size_t wrow = (br < 128) ? (size_t)(kb + br) : (size_t)(kDI + kb + br - 128);
      const unsigned short* wp = Win + wrow * kDM + k0;
      #pragma unroll
      for (int q = 0; q < 4; ++q) bv[q] = *(const uint4*)(wp + q * 8);
    }
    __syncthreads();   // prior MFMA done
    if (ar < 48) *(uint4*)&As[aq][ar][0] = *(const uint4*)av;
    #pragma unroll
    for (int q = 0; q < 4; ++q) *(uint4*)&Bs[q][tid][0] = bv[q];
    __syncthreads();
    short8 bfrag[4];
    #pragma unroll
    for (int ni = 0; ni < 4; ++ni)
      bfrag[ni] = *(const short8*)&Bs[lq][wn + ni * 16 + lm][0];
    #pragma unroll
    for (int mi = 0; mi < 3; ++mi) {
      short8 afrag = *(const short8*)&As[lq][mi * 16 + lm][0];
      #pragma unroll
      for (int ni = 0; ni < 4; ++ni)
        acc[mi][ni] = __builtin_amdgcn_mfma_f32_16x16x32_bf16(
            afrag, bfrag[ni], acc[mi][ni], 0, 0, 0);
    }
  }
  __syncthreads();

  // scatter acc: u_pre -> LDS; z -> silu -> sgT_bf global
  #pragma unroll
  for (int mi = 0; mi < 3; ++mi) {
    #pragma unroll
    for (int ni = 0; ni < 4; ++ni) {
      int col = wn + ni * 16 + lm;
      #pragma unroll
      for (int r = 0; r < 4; ++r) {
        int row = mi * 16 + lq * 4 + r;
        if (row < 35) {
          float v = acc[mi][ni][r];
          if (col < 128) {
            upre[row][col] = f2bf(v);
          } else if (row >= 3) {
            int t = bm + row - 3;
            sgT_bf[((size_t)(t >> 8) * kDI + kb + col - 128) * kL + (t & 255)] =
                f2bf(silu_f(v));
          }
        }
      }
    }
  }
  // stage Bs2 (Wx chunk) concurrently
  for (int idx = tid; idx < 64 * 16; idx += 256) {
    int row = idx >> 4, q = idx & 15;
    uint4 v;
    if (row < kPROJ)
      v = *(const uint4*)(Wx + (size_t)row * kDI + kb + q * 8);
    else
      v = make_uint4(0u, 0u, 0u, 0u);
    *(uint4*)&Bs2[row][q * 8] = v;
  }
  __syncthreads();

  // ---- Stage B: causal conv4 + SiLU ----
  {
    int dloc = tid & 127;
    int lh = tid >> 7;   // 0/1 -> 16 tokens each
    float w0 = scw[dloc][0], w1 = scw[dloc][1];
    float w2 = scw[dloc][2], w3 = scw[dloc][3];
    float cbv = scb[dloc];
    #pragma unroll
    for (int i = 0; i < 16; ++i) {
      int l = lh * 16 + i;
      float a = cbv;
      a = fmaf(bf2f(upre[l + 0][dloc]), w0, a);
      a = fmaf(bf2f(upre[l + 1][dloc]), w1, a);
      a = fmaf(bf2f(upre[l + 2][dloc]), w2, a);
      a = fmaf(bf2f(upre[l + 3][dloc]), w3, a);
      float uval = silu_f(a);
      unsigned short ub = f2bf(uval);
      xa[l][dloc] = ub;
      int t = bm + l;
      uT_bf[((size_t)(t >> 8) * kDI + kb + dloc) * kL + (t & 255)] = ub;
    }
  }
  __syncthreads();

  // ---- Stage C: x_proj MFMA (M=32, N=64(56), K=128; wave k-split) ----
  {
    int kq = wave;   // each wave one K=32 slice
    f32x4 acc2[2][4] = {};
    #pragma unroll
    for (int mi = 0; mi < 2; ++mi) {
      short8 afrag = *(const short8*)&xa[mi * 16 + lm][kq * 32 + lq * 8];
      #pragma unroll
      for (int ni = 0; ni < 4; ++ni) {
        short8 bfrag = *(const short8*)&Bs2[ni * 16 + lm][kq * 32 + lq * 8];
        acc2[mi][ni] = __builtin_amdgcn_mfma_f32_16x16x32_bf16(
            afrag, bfrag, acc2[mi][ni], 0, 0, 0);
      }
    }
    #pragma unroll
    for (int mi = 0; mi < 2; ++mi) {
      #pragma unroll
      for (int ni = 0; ni < 4; ++ni) {
        int col = ni * 16 + lm;
        if (col < kPROJ) {
          #pragma unroll
          for (int r = 0; r < 4; ++r) {
            int trow = bm + mi * 16 + lq * 4 + r;
            atomicAdd(&proj[(size_t)trow * kPROJ + col], acc2[mi][ni][r]);
          }
        }
      }
    }
  }
}

// ------------- bf16 MFMA NT GEMM (out_proj) + next-layer proj zeroing ------
__global__ __launch_bounds__(256) void bgemm_out_k(
    const unsigned short* __restrict__ A, int lda,
    const unsigned short* __restrict__ B, int ldb,
    float* __restrict__ C, int ldc, int Kc, float* __restrict__ proj_zero) {
  __shared__ __align__(16) unsigned short As[4][128][8];
  __shared__ __align__(16) unsigned short Bs[4][128][8];
  int tid = threadIdx.x;
  int bm = blockIdx.y * 128;
  int bn = blockIdx.x * 128;
  int k_begin = blockIdx.z * Kc;
  {
    int bid = (blockIdx.z * 16 + blockIdx.y) * 3 + blockIdx.x;  // 192 blocks
    for (int i = bid * 256 + tid; i < kTok * kPROJ; i += 192 * 256)
      proj_zero[i] = 0.f;
  }
  int wave = tid >> 6, lane = tid & 63;
  int lm = lane & 15, lq = lane >> 4;
  int wm = (wave >> 1) * 64, wn = (wave & 1) * 64;
  f32x4 acc[4][4] = {};

  for (int kt = 0; kt < Kc; kt += 32) {
    int k0 = k_begin + kt;
    int ar0 = tid & 127, aq0 = tid >> 7;
    int aq1 = aq0 + 2;
    uint4 a0 = *(const uint4*)(A + (size_t)(bm + ar0) * lda + k0 + aq0 * 8);
    uint4 a1 = *(const uint4*)(A + (size_t)(bm + ar0) * lda + k0 + aq1 * 8);
    uint4 b0 = *(const uint4*)(B + (size_t)(bn + ar0) * ldb + k0 + aq0 * 8);
    uint4 b1 = *(const uint4*)(B + (size_t)(bn + ar0) * ldb + k0 + aq1 * 8);
    __syncthreads();
    *(uint4*)&As[aq0][ar0][0] = a0;
    *(uint4*)&As[aq1][ar0][0] = a1;
    *(uint4*)&Bs[aq0][ar0][0] = b0;
    *(uint4*)&Bs[aq1][ar0][0] = b1;
    __syncthreads();
    short8 bfrag[4];
    #pragma unroll
    for (int ni = 0; ni < 4; ++ni)
      bfrag[ni] = *(const short8*)&Bs[lq][wn + ni * 16 + lm][0];
    #pragma unroll
    for (int mi = 0; mi < 4; ++mi) {
      short8 afrag = *(const short8*)&As[lq][wm + mi * 16 + lm][0];
      #pragma unroll
      for (int ni = 0; ni < 4; ++ni)
        acc[mi][ni] = __builtin_amdgcn_mfma_f32_16x16x32_bf16(
            afrag, bfrag[ni], acc[mi][ni], 0, 0, 0);
    }
  }

  #pragma unroll
  for (int mi = 0; mi < 4; ++mi) {
    #pragma unroll
    for (int ni = 0; ni < 4; ++ni) {
      int grow0 = bm + wm + mi * 16 + lq * 4;
      int gcol = bn + wn + ni * 16 + lm;
      #pragma unroll
      for (int r = 0; r < 4; ++r)
        atomicAdd(&C[(size_t)(grow0 + r) * ldc + gcol], acc[mi][ni][r]);
    }
  }
}

// ------------- split-state register scan + fused dt_proj -------------------
__global__ __launch_bounds__(256) void scansplit_k(
    const float* __restrict__ proj, const unsigned short* __restrict__ uT_bf,
    const unsigned short* __restrict__ sgT_bf, const float* __restrict__ dtw,
    const float* __restrict__ dtb, const float* __restrict__ A_log,
    const float* __restrict__ Dsk, unsigned short* __restrict__ y_bf) {
  int d0 = blockIdx.x * 8;
  int b = blockIdx.y;
  int tid = threadIdx.x;
  int dsub = tid & 7;
  int nh = (tid >> 3) & 1;
  int c = tid >> 4;
  int d = d0 + dsub;
  __shared__ float sh[16][16][9];
  __shared__ float sca[16][16][9];

  float Av[8];
  {
    const float* ap = A_log + (size_t)d * kDS + nh * 8;
    #pragma unroll
    for (int q = 0; q < 2; ++q) {
      float4 v = ((const float4*)ap)[q];
      Av[q * 4 + 0] = -__expf(v.x);
      Av[q * 4 + 1] = -__expf(v.y);
      Av[q * 4 + 2] = -__expf(v.z);
      Av[q * 4 + 3] = -__expf(v.w);
    }
  }
  float bdt = dtb[d];
  float Dv = Dsk[d];

  const float* pr = proj + ((size_t)(b * kL) + c * 16) * kPROJ;

  float dtlo[8], dthi[8];
  {
    float wdt[24];
    const float* wp = dtw + (size_t)d * kDTR;
    #pragma unroll
    for (int q = 0; q < 6; ++q) {
      float4 v = ((const float4*)wp)[q];
      wdt[q * 4 + 0] = v.x; wdt[q * 4 + 1] = v.y;
      wdt[q * 4 + 2] = v.z; wdt[q * 4 + 3] = v.w;
    }
    const float* prm = pr + (size_t)(nh * 8) * kPROJ;
    float mine[8];
    #pragma unroll
    for (int i = 0; i < 8; ++i) {
      const float* p = prm + (size_t)i * kPROJ;
      float acc = bdt;
      #pragma unroll
      for (int q = 0; q < 6; ++q) {
        float4 v = ((const float4*)p)[q];
        acc = fmaf(v.x, wdt[q * 4 + 0], acc);
        acc = fmaf(v.y, wdt[q * 4 + 1], acc);
        acc = fmaf(v.z, wdt[q * 4 + 2], acc);
        acc = fmaf(v.w, wdt[q * 4 + 3], acc);
      }
      mine[i] = softplus_f(acc);
    }
    #pragma unroll
    for (int i = 0; i < 8; ++i) {
      float other = __shfl_xor(mine[i], 8);
      dtlo[i] = nh ? other : mine[i];
      dthi[i] = nh ? mine[i] : other;
    }
  }

  float u_[16];
  {
    const unsigned short* up = uT_bf + ((size_t)b * kDI + d) * kL + c * 16;
    uint4 v0 = ((const uint4*)up)[0];
    uint4 v1 = ((const uint4*)up)[1];
    const unsigned short* us = (const unsigned short*)&v0;
    #pragma unroll
    for (int i = 0; i < 8; ++i) u_[i] = bf2f(us[i]);
    us = (const unsigned short*)&v1;
    #pragma unroll
    for (int i = 0; i < 8; ++i) u_[8 + i] = bf2f(us[i]);
  }

  float h[8], ca[8];
  #pragma unroll
  for (int n = 0; n < 8; ++n) { h[n] = 0.f; ca[n] = 1.f; }
  #pragma unroll
  for (int i = 0; i < 16; ++i) {
    float dl = (i < 8) ? dtlo[i] : dthi[i - 8];
    float du = dl * u_[i];
    const float* p = pr + (size_t)i * kPROJ + 24 + nh * 8;
    float4 b0 = ((const float4*)p)[0];
    float4 b1 = ((const float4*)p)[1];
    float Bv[8] = {b0.x, b0.y, b0.z, b0.w, b1.x, b1.y, b1.z, b1.w};
    #pragma unroll
    for (int n = 0; n < 8; ++n) {
      float a = __expf(dl * Av[n]);
      h[n] = fmaf(a, h[n], du * Bv[n]);
      ca[n] *= a;
    }
  }
  {
    int nrow = nh * 8;
    #pragma unroll
    for (int q = 0; q < 8; ++q) {
      sh[c][nrow + q][dsub] = h[q];
      sca[c][nrow + q][dsub] = ca[q];
    }
  }
  __syncthreads();

  float h0[8];
  #pragma unroll
  for (int n = 0; n < 8; ++n) h0[n] = 0.f;
  {
    int nrow = nh * 8;
    for (int j = 0; j < c; ++j) {
      #pragma unroll
      for (int q = 0; q < 8; ++q)
        h0[q] = fmaf(sca[j][nrow + q][dsub], h0[q], sh[j][nrow + q][dsub]);
    }
  }

  float sg_[16];
  if (nh == 0) {
    const unsigned short* sp = sgT_bf + ((size_t)b * kDI + d) * kL + c * 16;
    uint4 v0 = ((const uint4*)sp)[0];
    uint4 v1 = ((const uint4*)sp)[1];
    const unsigned short* ss = (const unsigned short*)&v0;
    #pragma unroll
    for (int i = 0; i < 8; ++i) sg_[i] = bf2f(ss[i]);
    ss = (const unsigned short*)&v1;
    #pragma unroll
    for (int i = 0; i < 8; ++i) sg_[8 + i] = bf2f(ss[i]);
  }

  unsigned short* yp = y_bf + (size_t)(b * kL + c * 16) * kDI + d;
  #pragma unroll
  for (int i = 0; i < 16; ++i) {
    float dl = (i < 8) ? dtlo[i] : dthi[i - 8];
    float du = dl * u_[i];
    const float* p = pr + (size_t)i * kPROJ + 24 + nh * 8;
    float4 b0 = ((const float4*)p)[0];
    float4 b1 = ((const float4*)p)[1];
    float4 c0 = ((const float4*)(p + 16))[0];
    float4 c1 = ((const float4*)(p + 16))[1];
    float Bv[8] = {b0.x, b0.y, b0.z, b0.w, b1.x, b1.y, b1.z, b1.w};
    float Cv[8] = {c0.x, c0.y, c0.z, c0.w, c1.x, c1.y, c1.z, c1.w};
    float yv = 0.f;
    #pragma unroll
    for (int n = 0; n < 8; ++n) {
      float a = __expf(dl * Av[n]);
      h0[n] = fmaf(a, h0[n], du * Bv[n]);
      yv = fmaf(h0[n], Cv[n], yv);
    }
    yv += __shfl_xor(yv, 8);
    if (nh == 0) yp[(size_t)i * kDI] = f2bf((yv + u_[i] * Dv) * sg_[i]);
  }
}

// ---------------- head ----------------
__global__ __launch_bounds__(64) void head_k(
    const float* __restrict__ pooled, const float* __restrict__ hw,
    const float* __restrict__ hb, float* __restrict__ out) {
  int b = blockIdx.x >> 2, c = blockIdx.x & 3;
  int lane = threadIdx.x;
  float acc = 0.f;
  for (int dd = lane; dd < kDM; dd += 64)
    acc = fmaf(pooled[b * kDM + dd], hw[c * kDM + dd], acc);
  #pragma unroll
  for (int m = 32; m >= 1; m >>= 1) acc += __shfl_xor(acc, m);
  if (lane == 0) out[b * 4 + c] = acc + hb[c];
}

}  // namespace

extern "C" void kernel_launch(void* const* d_in, const int* in_sizes, int n_in,
                              void* d_out, int out_size, void* d_ws, size_t ws_size,
                              hipStream_t stream) {
  (void)in_sizes; (void)n_in; (void)out_size; (void)ws_size;
  const float* x        = (const float*)d_in[0];
  const float* patch_w  = (const float*)d_in[1];
  const float* patch_b  = (const float*)d_in[2];
  const float* pos      = (const float*)d_in[3];
  const float* ln_g     = (const float*)d_in[4];
  const float* ln_b     = (const float*)d_in[5];
  const float* in_w     = (const float*)d_in[6];
  const float* conv_w   = (const float*)d_in[7];
  const float* conv_b   = (const float*)d_in[8];
  const float* xproj_w  = (const float*)d_in[9];
  const float* dtproj_w = (const float*)d_in[10];
  const float* dtproj_b = (const float*)d_in[11];
  const float* A_log    = (const float*)d_in[12];
  const float* Dskip    = (const float*)d_in[13];
  const float* out_w    = (const float*)d_in[14];
  const float* fn_g     = (const float*)d_in[15];
  const float* fn_b     = (const float*)d_in[16];
  const float* head_w   = (const float*)d_in[17];
  const float* head_b   = (const float*)d_in[18];
  float* out = (float*)d_out;

  float* ws = (float*)d_ws;
  float* tok    = ws; ws += kTok * kDM;       // fp32 residual
  float* proj   = ws; ws += kTok * kPROJ;     // [t][56] row-major
  float* pooled = ws; ws += kB * kDM;
  unsigned short* uT_bf  = (unsigned short*)ws; ws += kTok * kDI / 2;
  unsigned short* sgT_bf = (unsigned short*)ws; ws += kTok * kDI / 2;
  unsigned short* y_bf   = (unsigned short*)ws; ws += kTok * kDI / 2;
  unsigned short* w_bf   = (unsigned short*)ws; ws += (size_t)kNL * kWTOT / 2;

  // all-layer weight cast + pooled zero-init (once per call)
  convert_all_k<<<dim3(kWTOT / 4 / 256, kNL), 256, 0, stream>>>(
      in_w, out_w, xproj_w, w_bf, pooled);

  // Patch embedding fused: im2col + GEMM + bias + pos (+ layer-0 proj zero)
  patch_gemm_k<<<dim3(6, 32), 256, 0, stream>>>(x, patch_w, patch_b, pos, tok,
                                                proj);

  for (int layer = 0; layer < kNL; ++layer) {
    const unsigned short* wl = w_bf + (size_t)layer * kWTOT;
    // fused LN + in_proj + conv + SiLU + z-gate + x_proj  (384 blocks)
    fused1_k<<<dim3(64, 6), 256, 0, stream>>>(
        tok, wl, wl + kWIN + kWOUT, ln_g + layer * kDM, ln_b + layer * kDM,
        conv_w + layer * kDI * 4, conv_b + layer * kDI, proj, uT_bf, sgT_bf);
    // split-state register scan + fused dt_proj -> y_bf (768 blocks)
    scansplit_k<<<dim3(kDI / 8, kB), 256, 0, stream>>>(
        proj, uT_bf, sgT_bf, dtproj_w + (size_t)layer * kDI * kDTR,
        dtproj_b + layer * kDI, A_log + (size_t)layer * kDI * kDS,
        Dskip + layer * kDI, y_bf);
    // out_proj (MFMA, split-K=4, atomic into residual) + next proj zero
    bgemm_out_k<<<dim3(3, 16, 4), 256, 0, stream>>>(
        y_bf, kDI, wl + kWIN, kDI, tok, kDM, kDI / 4, proj);
  }

  // final LN + fused mean-pool (atomicAdd into pre-zeroed pooled)
  lnpool_k<<<kTok, kDM, 0, stream>>>(tok, pooled, fn_g, fn_b);
  head_k<<<kB * 4, 64, 0, stream>>>(pooled, head_w, head_b, out);
}

// Round 17
// 1144.737 us; speedup vs baseline: 1.2943x; 1.2943x over previous
//
#include <hip/hip_runtime.h>
#include <math.h>

namespace {

constexpr int kB   = 8;
constexpr int kL   = 256;
constexpr int kTok = 2048;   // B*L
constexpr int kDM  = 384;
constexpr int kDI  = 768;
constexpr int kDS  = 16;
constexpr int kDTR = 24;
constexpr int kPROJ = 56;    // DTR + 2*DS
constexpr int kNL  = 12;

constexpr int kWIN  = 2 * kDI * kDM;   // 589824 in_proj weights/layer
constexpr int kWOUT = kDM * kDI;       // 294912
constexpr int kWX   = kPROJ * kDI;     // 43008
constexpr int kWTOT = kWIN + kWOUT + kWX;  // 927744

typedef float f32x4 __attribute__((ext_vector_type(4)));
typedef short short8 __attribute__((ext_vector_type(8)));

__device__ __forceinline__ float softplus_f(float x) {
  return (x > 20.f) ? x : log1pf(__expf(x));
}
__device__ __forceinline__ float silu_f(float x) {
  return x / (1.f + __expf(-x));
}
__device__ __forceinline__ unsigned short f2bf(float f) {
  union { float f; unsigned u; } v; v.f = f;
  unsigned r = v.u + 0x7FFFu + ((v.u >> 16) & 1u);
  return (unsigned short)(r >> 16);
}
__device__ __forceinline__ float bf2f(unsigned short u) {
  return __uint_as_float((unsigned)u << 16);
}

// ------------- patch embed GEMM: tok = im2col(x)·patch_w^T + b + pos -------
__global__ __launch_bounds__(256) void patch_gemm_k(
    const float* __restrict__ x, const float* __restrict__ Bw,
    const float* __restrict__ bias, const float* __restrict__ pos,
    float* __restrict__ C) {
  __shared__ float As[16][68];
  __shared__ float Bs[16][68];
  int tid = threadIdx.x;
  int bm = blockIdx.y * 64;
  int bn = blockIdx.x * 64;
  int lr = tid >> 2;
  int lk = (tid & 3) << 2;
  int tm = (tid >> 4) << 2;
  int tn = (tid & 15) << 2;
  float acc[4][4] = {};
  for (int k0 = 0; k0 < 256; k0 += 16) {
    {
      int token = bm + lr;
      int b = token >> 8, l = token & 255;
      int h = l >> 3, w = l & 7;
      int p = k0 >> 4;
      const float* ap = x + ((size_t)(b * 512) + h * 16 + p) * 128 + w * 16 + lk;
      float4 av = *(const float4*)ap;
      As[lk + 0][lr] = av.x; As[lk + 1][lr] = av.y;
      As[lk + 2][lr] = av.z; As[lk + 3][lr] = av.w;
    }
    {
      const float* bp = Bw + (size_t)(bn + lr) * 256 + k0 + lk;
      float4 bv = *(const float4*)bp;
      Bs[lk + 0][lr] = bv.x; Bs[lk + 1][lr] = bv.y;
      Bs[lk + 2][lr] = bv.z; Bs[lk + 3][lr] = bv.w;
    }
    __syncthreads();
    #pragma unroll
    for (int k = 0; k < 16; ++k) {
      float4 a = *(const float4*)&As[k][tm];
      float4 b = *(const float4*)&Bs[k][tn];
      float av[4] = {a.x, a.y, a.z, a.w};
      float bv[4] = {b.x, b.y, b.z, b.w};
      #pragma unroll
      for (int i = 0; i < 4; ++i)
        #pragma unroll
        for (int j = 0; j < 4; ++j)
          acc[i][j] = fmaf(av[i], bv[j], acc[i][j]);
    }
    __syncthreads();
  }
  #pragma unroll
  for (int i = 0; i < 4; ++i) {
    int row = bm + tm + i;
    #pragma unroll
    for (int j = 0; j < 4; ++j) {
      int col = bn + tn + j;
      C[(size_t)row * kDM + col] =
          acc[i][j] + bias[col] + pos[(size_t)(row & 255) * kDM + col];
    }
  }
}

// ------------- final layernorm + fused mean-pool (atomicAdd) ---------------
__global__ __launch_bounds__(384) void lnpool_k(
    const float* __restrict__ in, float* __restrict__ pooled,
    const float* __restrict__ g, const float* __restrict__ bb) {
  int t = blockIdx.x, d = threadIdx.x;
  float v = in[(size_t)t * kDM + d];
  float s = v, s2 = v * v;
  #pragma unroll
  for (int m = 32; m >= 1; m >>= 1) {
    s  += __shfl_xor(s, m);
    s2 += __shfl_xor(s2, m);
  }
  __shared__ float ps[6], ps2[6];
  if ((d & 63) == 0) { ps[d >> 6] = s; ps2[d >> 6] = s2; }
  __syncthreads();
  float S = 0.f, S2 = 0.f;
  #pragma unroll
  for (int i = 0; i < 6; ++i) { S += ps[i]; S2 += ps2[i]; }
  float mean = S * (1.f / 384.f);
  float var  = S2 * (1.f / 384.f) - mean * mean;
  float r = rsqrtf(var + 1e-5f);
  float o = (v - mean) * r * g[d] + bb[d];
  atomicAdd(&pooled[(size_t)(t >> 8) * kDM + d], o * (1.f / 256.f));
}

// ------------- convert ALL layers' GEMM weights fp32 -> bf16 (+pool zero) --
__global__ __launch_bounds__(256) void convert_all_k(
    const float* __restrict__ w_in, const float* __restrict__ w_out,
    const float* __restrict__ w_x, unsigned short* __restrict__ dst,
    float* __restrict__ pooled_zero) {
  int layer = blockIdx.y;
  int tid = threadIdx.x;
  if (layer == 0 && blockIdx.x == 0) {
    for (int i = tid; i < kB * kDM; i += 256) pooled_zero[i] = 0.f;
  }
  int i4 = (blockIdx.x * 256 + tid) * 4;
  if (i4 >= kWTOT) return;
  const float* src;
  int off;
  if (i4 < kWIN) { src = w_in + (size_t)layer * kWIN; off = i4; }
  else if (i4 < kWIN + kWOUT) { src = w_out + (size_t)layer * kWOUT; off = i4 - kWIN; }
  else { src = w_x + (size_t)layer * kWX; off = i4 - kWIN - kWOUT; }
  float4 v = *(const float4*)(src + off);
  unsigned short o[4] = {f2bf(v.x), f2bf(v.y), f2bf(v.z), f2bf(v.w)};
  *(uint2*)(dst + (size_t)layer * kWTOT + i4) = *(const uint2*)o;
}

// ------------- in_proj with fused LayerNorm (+ proj zeroing), 64x128 -------
// xz_bf[2048,1536] = LN(tok)[2048,384] · W[1536,384]^T  (bf16 MFMA, bf16 out)
// grid (12, 32) = 384 blocks.
__global__ __launch_bounds__(256) void inproj_ln_k(
    const float* __restrict__ tok, const unsigned short* __restrict__ Bw,
    const float* __restrict__ g, const float* __restrict__ bb,
    unsigned short* __restrict__ Cbf, float* __restrict__ proj_zero) {
  __shared__ __align__(16) unsigned short As[4][64][8];
  __shared__ __align__(16) unsigned short Bs[4][128][8];
  __shared__ float smean[64], srstd[64];
  __shared__ float sg_[kDM], sb_[kDM];
  int tid = threadIdx.x;
  int bm = blockIdx.y * 64;
  int bn = blockIdx.x * 128;
  // proj zeroing for the upcoming split-K atomics (384 blocks cover it)
  {
    int bid = blockIdx.y * 12 + blockIdx.x;
    for (int i = bid * 256 + tid; i < kTok * kPROJ; i += 384 * 256)
      proj_zero[i] = 0.f;
  }
  for (int i = tid; i < kDM; i += 256) { sg_[i] = g[i]; sb_[i] = bb[i]; }
  // LN stats prepass: 4 threads per row
  {
    int r = tid >> 2, quarter = tid & 3;
    const float* rp = tok + (size_t)(bm + r) * kDM + quarter * 96;
    float s = 0.f, s2 = 0.f;
    #pragma unroll
    for (int q = 0; q < 24; ++q) {
      float4 v = ((const float4*)rp)[q];
      s  += v.x + v.y + v.z + v.w;
      s2 += v.x * v.x + v.y * v.y + v.z * v.z + v.w * v.w;
    }
    s  += __shfl_xor(s, 1);  s2 += __shfl_xor(s2, 1);
    s  += __shfl_xor(s, 2);  s2 += __shfl_xor(s2, 2);
    if (quarter == 0) {
      float mean = s * (1.f / 384.f);
      float var  = s2 * (1.f / 384.f) - mean * mean;
      smean[r] = mean;
      srstd[r] = rsqrtf(var + 1e-5f);
    }
  }
  __syncthreads();
  int wave = tid >> 6, lane = tid & 63;
  int lm = lane & 15, lq = lane >> 4;
  int wm = (wave & 1) * 32, wn = (wave >> 1) * 64;
  f32x4 acc[2][4] = {};
  for (int k0 = 0; k0 < kDM; k0 += 32) {
    int ar = tid & 63, aq = tid >> 6;  // aq 0..3 (k-quad)
    unsigned short av[8];
    {
      float mean = smean[ar], rstd = srstd[ar];
      const float* ap = tok + (size_t)(bm + ar) * kDM + k0 + aq * 8;
      float4 v0 = ((const float4*)ap)[0];
      float4 v1 = ((const float4*)ap)[1];
      float vv[8] = {v0.x, v0.y, v0.z, v0.w, v1.x, v1.y, v1.z, v1.w};
      #pragma unroll
      for (int j = 0; j < 8; ++j) {
        int k = k0 + aq * 8 + j;
        av[j] = f2bf((vv[j] - mean) * rstd * sg_[k] + sb_[k]);
      }
    }
    int br = tid & 127, bq0 = tid >> 7, bq1 = bq0 + 2;
    uint4 b0 = *(const uint4*)(Bw + (size_t)(bn + br) * kDM + k0 + bq0 * 8);
    uint4 b1 = *(const uint4*)(Bw + (size_t)(bn + br) * kDM + k0 + bq1 * 8);
    __syncthreads();
    *(uint4*)&As[aq][ar][0]  = *(const uint4*)av;
    *(uint4*)&Bs[bq0][br][0] = b0;
    *(uint4*)&Bs[bq1][br][0] = b1;
    __syncthreads();
    short8 bfrag[4];
    #pragma unroll
    for (int ni = 0; ni < 4; ++ni)
      bfrag[ni] = *(const short8*)&Bs[lq][wn + ni * 16 + lm][0];
    #pragma unroll
    for (int mi = 0; mi < 2; ++mi) {
      short8 afrag = *(const short8*)&As[lq][wm + mi * 16 + lm][0];
      #pragma unroll
      for (int ni = 0; ni < 4; ++ni)
        acc[mi][ni] = __builtin_amdgcn_mfma_f32_16x16x32_bf16(
            afrag, bfrag[ni], acc[mi][ni], 0, 0, 0);
    }
  }
  #pragma unroll
  for (int mi = 0; mi < 2; ++mi) {
    #pragma unroll
    for (int ni = 0; ni < 4; ++ni) {
      int grow0 = bm + wm + mi * 16 + lq * 4;
      int gcol = bn + wn + ni * 16 + lm;
      #pragma unroll
      for (int r = 0; r < 4; ++r)
        Cbf[(size_t)(grow0 + r) * (2 * kDI) + gcol] = f2bf(acc[mi][ni][r]);
    }
  }
}

// ------------- x_proj with fused depthwise conv + SiLU + z-gate ------------
// grid (32, 6) = 192 blocks. Side outputs: uT_bf[b][d][l] and
// sgT_bf[b][d][l] = silu(z) (both bf16, lane-contiguous along l).
__global__ __launch_bounds__(256) void xproj_conv_k(
    const unsigned short* __restrict__ xz, const unsigned short* __restrict__ Bw,
    const float* __restrict__ cw, const float* __restrict__ cb,
    float* __restrict__ proj, unsigned short* __restrict__ uT_bf,
    unsigned short* __restrict__ sgT_bf) {
  __shared__ __align__(16) unsigned short As[4][64][8];
  __shared__ __align__(16) unsigned short Bs[4][64][8];
  __shared__ float scw[128][4];
  __shared__ float scb[128];
  int tid = threadIdx.x;
  int bm = blockIdx.x * 64;       // token tile
  int kbase = blockIdx.y * 128;   // d chunk (split-K = 6)
  int wave = tid >> 6, lane = tid & 63;
  int lm = lane & 15, lq = lane >> 4;
  int wm = wave * 16;
  f32x4 acc[4] = {};

  if (tid < 128) {
    *(float4*)&scw[tid][0] = *(const float4*)(cw + (size_t)(kbase + tid) * 4);
    scb[tid] = cb[kbase + tid];
  }
  __syncthreads();

  int ar = tid & 63;
  int aq = tid >> 6;   // 0..3
  int t = bm + ar;
  int b = t >> 8, l = t & 255;

  for (int kt = 0; kt < 4; ++kt) {
    int k0 = kbase + kt * 32;
    int dloc = kt * 32 + aq * 8;
    int dg = kbase + dloc;
    unsigned short av[8];
    {
      float vals[4][8];
      #pragma unroll
      for (int q = 0; q < 4; ++q) {
        if (l - 3 + q >= 0) {
          uint4 r = *(const uint4*)(xz + (size_t)(t - 3 + q) * (2 * kDI) + dg);
          const unsigned short* rs = (const unsigned short*)&r;
          #pragma unroll
          for (int j = 0; j < 8; ++j) vals[q][j] = bf2f(rs[j]);
        } else {
          #pragma unroll
          for (int j = 0; j < 8; ++j) vals[q][j] = 0.f;
        }
      }
      // z-gate for the same 8 channels (row t, offset +768)
      uint4 zr = *(const uint4*)(xz + (size_t)t * (2 * kDI) + kDI + dg);
      const unsigned short* zs = (const unsigned short*)&zr;
      #pragma unroll
      for (int j = 0; j < 8; ++j) {
        float a = scb[dloc + j];
        a = fmaf(vals[0][j], scw[dloc + j][0], a);
        a = fmaf(vals[1][j], scw[dloc + j][1], a);
        a = fmaf(vals[2][j], scw[dloc + j][2], a);
        a = fmaf(vals[3][j], scw[dloc + j][3], a);
        unsigned short ub = f2bf(silu_f(a));
        av[j] = ub;
        size_t rbase = ((size_t)b * kDI + dg + j) * kL + l;
        uT_bf[rbase] = ub;
        sgT_bf[rbase] = f2bf(silu_f(bf2f(zs[j])));
      }
    }
    int br = tid & 63, bq = tid >> 6;
    uint4 b0;
    if (br < kPROJ)
      b0 = *(const uint4*)(Bw + (size_t)br * kDI + k0 + bq * 8);
    else
      b0 = make_uint4(0u, 0u, 0u, 0u);
    __syncthreads();
    *(uint4*)&As[aq][ar][0] = *(const uint4*)av;
    *(uint4*)&Bs[bq][br][0] = b0;
    __syncthreads();
    short8 afrag = *(const short8*)&As[lq][wm + lm][0];
    #pragma unroll
    for (int ni = 0; ni < 4; ++ni) {
      short8 bfrag = *(const short8*)&Bs[lq][ni * 16 + lm][0];
      acc[ni] = __builtin_amdgcn_mfma_f32_16x16x32_bf16(
          afrag, bfrag, acc[ni], 0, 0, 0);
    }
  }

  #pragma unroll
  for (int ni = 0; ni < 4; ++ni) {
    int grow0 = bm + wm + lq * 4;
    int gcol = ni * 16 + lm;
    if (gcol < kPROJ) {
      #pragma unroll
      for (int r = 0; r < 4; ++r)
        atomicAdd(&proj[(size_t)(grow0 + r) * kPROJ + gcol], acc[ni][r]);
    }
  }
}

// ------------- bf16 MFMA NT GEMM (out_proj): atomicAdd into residual -------
__global__ __launch_bounds__(256) void bgemm_out_k(
    const unsigned short* __restrict__ A, int lda,
    const unsigned short* __restrict__ B, int ldb,
    float* __restrict__ C, int ldc, int Kc) {
  __shared__ __align__(16) unsigned short As[4][128][8];
  __shared__ __align__(16) unsigned short Bs[4][128][8];
  int tid = threadIdx.x;
  int bm = blockIdx.y * 128;
  int bn = blockIdx.x * 128;
  int k_begin = blockIdx.z * Kc;
  int wave = tid >> 6, lane = tid & 63;
  int lm = lane & 15, lq = lane >> 4;
  int wm = (wave >> 1) * 64, wn = (wave & 1) * 64;
  f32x4 acc[4][4] = {};

  for (int kt = 0; kt < Kc; kt += 32) {
    int k0 = k_begin + kt;
    int ar0 = tid & 127, aq0 = tid >> 7;
    int aq1 = aq0 + 2;
    uint4 a0 = *(const uint4*)(A + (size_t)(bm + ar0) * lda + k0 + aq0 * 8);
    uint4 a1 = *(const uint4*)(A + (size_t)(bm + ar0) * lda + k0 + aq1 * 8);
    uint4 b0 = *(const uint4*)(B + (size_t)(bn + ar0) * ldb + k0 + aq0 * 8);
    uint4 b1 = *(const uint4*)(B + (size_t)(bn + ar0) * ldb + k0 + aq1 * 8);
    __syncthreads();
    *(uint4*)&As[aq0][ar0][0] = a0;
    *(uint4*)&As[aq1][ar0][0] = a1;
    *(uint4*)&Bs[aq0][ar0][0] = b0;
    *(uint4*)&Bs[aq1][ar0][0] = b1;
    __syncthreads();
    short8 bfrag[4];
    #pragma unroll
    for (int ni = 0; ni < 4; ++ni)
      bfrag[ni] = *(const short8*)&Bs[lq][wn + ni * 16 + lm][0];
    #pragma unroll
    for (int mi = 0; mi < 4; ++mi) {
      short8 afrag = *(const short8*)&As[lq][wm + mi * 16 + lm][0];
      #pragma unroll
      for (int ni = 0; ni < 4; ++ni)
        acc[mi][ni] = __builtin_amdgcn_mfma_f32_16x16x32_bf16(
            afrag, bfrag[ni], acc[mi][ni], 0, 0, 0);
    }
  }

  #pragma unroll
  for (int mi = 0; mi < 4; ++mi) {
    #pragma unroll
    for (int ni = 0; ni < 4; ++ni) {
      int grow0 = bm + wm + mi * 16 + lq * 4;
      int gcol = bn + wn + ni * 16 + lm;
      #pragma unroll
      for (int r = 0; r < 4; ++r)
        atomicAdd(&C[(size_t)(grow0 + r) * ldc + gcol], acc[mi][ni][r]);
    }
  }
}

// ------------- split-state register scan + fused dt_proj -------------------
// thread = (chunk c[16], state-half nh[2], dsub[8]); 8 SSM states/thread.
// u and silu(z) both from bf16 transposed buffers (coalesced uint4 loads).
__global__ __launch_bounds__(256) void scansplit_k(
    const float* __restrict__ proj, const unsigned short* __restrict__ uT_bf,
    const unsigned short* __restrict__ sgT_bf, const float* __restrict__ dtw,
    const float* __restrict__ dtb, const float* __restrict__ A_log,
    const float* __restrict__ Dsk, unsigned short* __restrict__ y_bf) {
  int d0 = blockIdx.x * 8;
  int b = blockIdx.y;
  int tid = threadIdx.x;
  int dsub = tid & 7;
  int nh = (tid >> 3) & 1;
  int c = tid >> 4;
  int d = d0 + dsub;
  __shared__ float sh[16][16][9];
  __shared__ float sca[16][16][9];

  float Av[8];
  {
    const float* ap = A_log + (size_t)d * kDS + nh * 8;
    #pragma unroll
    for (int q = 0; q < 2; ++q) {
      float4 v = ((const float4*)ap)[q];
      Av[q * 4 + 0] = -__expf(v.x);
      Av[q * 4 + 1] = -__expf(v.y);
      Av[q * 4 + 2] = -__expf(v.z);
      Av[q * 4 + 3] = -__expf(v.w);
    }
  }
  float bdt = dtb[d];
  float Dv = Dsk[d];

  const float* pr = proj + ((size_t)(b * kL) + c * 16) * kPROJ;

  // dt: my 8 tokens (l = c*16 + nh*8 + i), partner's 8 via shuffle
  float dtlo[8], dthi[8];
  {
    float wdt[24];
    const float* wp = dtw + (size_t)d * kDTR;
    #pragma unroll
    for (int q = 0; q < 6; ++q) {
      float4 v = ((const float4*)wp)[q];
      wdt[q * 4 + 0] = v.x; wdt[q * 4 + 1] = v.y;
      wdt[q * 4 + 2] = v.z; wdt[q * 4 + 3] = v.w;
    }
    const float* prm = pr + (size_t)(nh * 8) * kPROJ;
    float mine[8];
    #pragma unroll
    for (int i = 0; i < 8; ++i) {
      const float* p = prm + (size_t)i * kPROJ;
      float acc = bdt;
      #pragma unroll
      for (int q = 0; q < 6; ++q) {
        float4 v = ((const float4*)p)[q];
        acc = fmaf(v.x, wdt[q * 4 + 0], acc);
        acc = fmaf(v.y, wdt[q * 4 + 1], acc);
        acc = fmaf(v.z, wdt[q * 4 + 2], acc);
        acc = fmaf(v.w, wdt[q * 4 + 3], acc);
      }
      mine[i] = softplus_f(acc);
    }
    #pragma unroll
    for (int i = 0; i < 8; ++i) {
      float other = __shfl_xor(mine[i], 8);
      dtlo[i] = nh ? other : mine[i];
      dthi[i] = nh ? mine[i] : other;
    }
  }

  float u_[16];
  {
    const unsigned short* up = uT_bf + ((size_t)b * kDI + d) * kL + c * 16;
    uint4 v0 = ((const uint4*)up)[0];
    uint4 v1 = ((const uint4*)up)[1];
    const unsigned short* us = (const unsigned short*)&v0;
    #pragma unroll
    for (int i = 0; i < 8; ++i) u_[i] = bf2f(us[i]);
    us = (const unsigned short*)&v1;
    #pragma unroll
    for (int i = 0; i < 8; ++i) u_[8 + i] = bf2f(us[i]);
  }

  // pass 1: local chunk scan over my 8 states
  float h[8], ca[8];
  #pragma unroll
  for (int n = 0; n < 8; ++n) { h[n] = 0.f; ca[n] = 1.f; }
  #pragma unroll
  for (int i = 0; i < 16; ++i) {
    float dl = (i < 8) ? dtlo[i] : dthi[i - 8];
    float du = dl * u_[i];
    const float* p = pr + (size_t)i * kPROJ + 24 + nh * 8;
    float4 b0 = ((const float4*)p)[0];
    float4 b1 = ((const float4*)p)[1];
    float Bv[8] = {b0.x, b0.y, b0.z, b0.w, b1.x, b1.y, b1.z, b1.w};
    #pragma unroll
    for (int n = 0; n < 8; ++n) {
      float a = __expf(dl * Av[n]);
      h[n] = fmaf(a, h[n], du * Bv[n]);
      ca[n] *= a;
    }
  }
  {
    int nrow = nh * 8;
    #pragma unroll
    for (int q = 0; q < 8; ++q) {
      sh[c][nrow + q][dsub] = h[q];
      sca[c][nrow + q][dsub] = ca[q];
    }
  }
  __syncthreads();

  // chunk-prefix combine
  float h0[8];
  #pragma unroll
  for (int n = 0; n < 8; ++n) h0[n] = 0.f;
  {
    int nrow = nh * 8;
    for (int j = 0; j < c; ++j) {
      #pragma unroll
      for (int q = 0; q < 8; ++q)
        h0[q] = fmaf(sca[j][nrow + q][dsub], h0[q], sh[j][nrow + q][dsub]);
    }
  }

  // z-gate for nh==0 half: coalesced bf16 loads from sgT_bf
  float sg_[16];
  if (nh == 0) {
    const unsigned short* sp = sgT_bf + ((size_t)b * kDI + d) * kL + c * 16;
    uint4 v0 = ((const uint4*)sp)[0];
    uint4 v1 = ((const uint4*)sp)[1];
    const unsigned short* ss = (const unsigned short*)&v0;
    #pragma unroll
    for (int i = 0; i < 8; ++i) sg_[i] = bf2f(ss[i]);
    ss = (const unsigned short*)&v1;
    #pragma unroll
    for (int i = 0; i < 8; ++i) sg_[8 + i] = bf2f(ss[i]);
  }

  // pass 2: true scan from h0; partial y over my 8 states; 1 shuffle; store
  unsigned short* yp = y_bf + (size_t)(b * kL + c * 16) * kDI + d;
  #pragma unroll
  for (int i = 0; i < 16; ++i) {
    float dl = (i < 8) ? dtlo[i] : dthi[i - 8];
    float du = dl * u_[i];
    const float* p = pr + (size_t)i * kPROJ + 24 + nh * 8;
    float4 b0 = ((const float4*)p)[0];
    float4 b1 = ((const float4*)p)[1];
    float4 c0 = ((const float4*)(p + 16))[0];
    float4 c1 = ((const float4*)(p + 16))[1];
    float Bv[8] = {b0.x, b0.y, b0.z, b0.w, b1.x, b1.y, b1.z, b1.w};
    float Cv[8] = {c0.x, c0.y, c0.z, c0.w, c1.x, c1.y, c1.z, c1.w};
    float yv = 0.f;
    #pragma unroll
    for (int n = 0; n < 8; ++n) {
      float a = __expf(dl * Av[n]);
      h0[n] = fmaf(a, h0[n], du * Bv[n]);
      yv = fmaf(h0[n], Cv[n], yv);
    }
    yv += __shfl_xor(yv, 8);
    if (nh == 0) yp[(size_t)i * kDI] = f2bf((yv + u_[i] * Dv) * sg_[i]);
  }
}

// ---------------- head ----------------
__global__ __launch_bounds__(64) void head_k(
    const float* __restrict__ pooled, const float* __restrict__ hw,
    const float* __restrict__ hb, float* __restrict__ out) {
  int b = blockIdx.x >> 2, c = blockIdx.x & 3;
  int lane = threadIdx.x;
  float acc = 0.f;
  for (int dd = lane; dd < kDM; dd += 64)
    acc = fmaf(pooled[b * kDM + dd], hw[c * kDM + dd], acc);
  #pragma unroll
  for (int m = 32; m >= 1; m >>= 1) acc += __shfl_xor(acc, m);
  if (lane == 0) out[b * 4 + c] = acc + hb[c];
}

}  // namespace

extern "C" void kernel_launch(void* const* d_in, const int* in_sizes, int n_in,
                              void* d_out, int out_size, void* d_ws, size_t ws_size,
                              hipStream_t stream) {
  (void)in_sizes; (void)n_in; (void)out_size; (void)ws_size;
  const float* x        = (const float*)d_in[0];
  const float* patch_w  = (const float*)d_in[1];
  const float* patch_b  = (const float*)d_in[2];
  const float* pos      = (const float*)d_in[3];
  const float* ln_g     = (const float*)d_in[4];
  const float* ln_b     = (const float*)d_in[5];
  const float* in_w     = (const float*)d_in[6];
  const float* conv_w   = (const float*)d_in[7];
  const float* conv_b   = (const float*)d_in[8];
  const float* xproj_w  = (const float*)d_in[9];
  const float* dtproj_w = (const float*)d_in[10];
  const float* dtproj_b = (const float*)d_in[11];
  const float* A_log    = (const float*)d_in[12];
  const float* Dskip    = (const float*)d_in[13];
  const float* out_w    = (const float*)d_in[14];
  const float* fn_g     = (const float*)d_in[15];
  const float* fn_b     = (const float*)d_in[16];
  const float* head_w   = (const float*)d_in[17];
  const float* head_b   = (const float*)d_in[18];
  float* out = (float*)d_out;

  float* ws = (float*)d_ws;
  float* tok    = ws; ws += kTok * kDM;       // fp32 residual
  float* proj   = ws; ws += kTok * kPROJ;     // [t][56] row-major
  float* pooled = ws; ws += kB * kDM;
  unsigned short* xz_bf  = (unsigned short*)ws; ws += kTok * 2 * kDI / 2;
  unsigned short* uT_bf  = (unsigned short*)ws; ws += kTok * kDI / 2;
  unsigned short* sgT_bf = (unsigned short*)ws; ws += kTok * kDI / 2;
  unsigned short* y_bf   = (unsigned short*)ws; ws += kTok * kDI / 2;
  unsigned short* w_bf   = (unsigned short*)ws; ws += (size_t)kNL * kWTOT / 2;

  // all-layer weight cast + pooled zero-init (once per call)
  convert_all_k<<<dim3(kWTOT / 4 / 256, kNL), 256, 0, stream>>>(
      in_w, out_w, xproj_w, w_bf, pooled);

  // Patch embedding fused: im2col + GEMM + bias + pos
  patch_gemm_k<<<dim3(6, 32), 256, 0, stream>>>(x, patch_w, patch_b, pos, tok);

  for (int layer = 0; layer < kNL; ++layer) {
    const unsigned short* wl = w_bf + (size_t)layer * kWTOT;
    // in_proj with fused LN (+ proj zero): LN(tok) x W^T -> xz_bf  (384 blk)
    inproj_ln_k<<<dim3(12, 32), 256, 0, stream>>>(
        tok, wl, ln_g + layer * kDM, ln_b + layer * kDM, xz_bf, proj);
    // x_proj with fused conv+SiLU+z-gate: proj += u·Wx^T ; uT_bf, sgT_bf
    xproj_conv_k<<<dim3(32, 6), 256, 0, stream>>>(
        xz_bf, wl + kWIN + kWOUT, conv_w + layer * kDI * 4,
        conv_b + layer * kDI, proj, uT_bf, sgT_bf);
    // split-state register scan + fused dt_proj -> y_bf (768 blk)
    scansplit_k<<<dim3(kDI / 8, kB), 256, 0, stream>>>(
        proj, uT_bf, sgT_bf, dtproj_w + (size_t)layer * kDI * kDTR,
        dtproj_b + layer * kDI, A_log + (size_t)layer * kDI * kDS,
        Dskip + layer * kDI, y_bf);
    // out_proj (MFMA, split-K=4, atomic into residual): tok += y x W^T
    bgemm_out_k<<<dim3(3, 16, 4), 256, 0, stream>>>(
        y_bf, kDI, wl + kWIN, kDI, tok, kDM, kDI / 4);
  }

  // final LN + fused mean-pool (atomicAdd into pre-zeroed pooled)
  lnpool_k<<<kTok, kDM, 0, stream>>>(tok, pooled, fn_g, fn_b);
  head_k<<<kB * 4, 64, 0, stream>>>(pooled, head_w, head_b, out);
}